// Round 1
// baseline (6011.021 us; speedup 1.0000x reference)
//
#include <hip/hip_runtime.h>
#include <cstddef>

// Problem constants
constexpr int Bc  = 4;
constexpr int Sc  = 512;
constexpr int Dc  = 1024;
constexpr int Hc  = 16;
constexpr int DHc = 64;
constexpr int DFFc = 4096;
constexpr int Lc  = 6;
constexpr int Mrows = Bc * Sc;          // 2048 token rows
constexpr float LN_EPS = 1e-5f;
constexpr float INV_SQRT_DK = 0.125f;   // 1/sqrt(64)
constexpr float NEG_BIG = -1e30f;

// ---------------------------------------------------------------------------
// Embedding: x[row] = word_emb[tok] + pos_table[tok]
// grid = 2048 blocks, 256 threads; 1024 floats/row = 256 float4
// ---------------------------------------------------------------------------
__global__ __launch_bounds__(256) void embed_kernel(
    const int* __restrict__ enc, const float* __restrict__ we,
    const float* __restrict__ pt, float* __restrict__ x) {
  int row = blockIdx.x;
  int tok = enc[row];
  const float4* wrow = (const float4*)(we + (size_t)tok * Dc);
  const float4* prow = (const float4*)(pt + (size_t)tok * Dc);
  float4* xrow = (float4*)(x + (size_t)row * Dc);
  int i = threadIdx.x;
  float4 a = wrow[i];
  float4 b = prow[i];
  xrow[i] = make_float4(a.x + b.x, a.y + b.y, a.z + b.z, a.w + b.w);
}

// ---------------------------------------------------------------------------
// fp32 tiled GEMM: C[M,N] = act(A[M,K] @ W[K,N] + bias[N] (+ R[M,N]))
// BM=BN=64, BK=16, 256 threads, 4x4 micro-tile per thread.
// grid = (N/64, M/64)
// ---------------------------------------------------------------------------
template <bool RELU, bool RES>
__global__ __launch_bounds__(256) void gemm_kernel(
    const float* __restrict__ A, const float* __restrict__ W,
    const float* __restrict__ bias, const float* __restrict__ R,
    float* __restrict__ C, int N, int K) {
  __shared__ float As[16][68];  // transposed: As[k][m], pad 68 for bank spread
  __shared__ float Bs[16][68];  // Bs[k][n]

  const int tid = threadIdx.x;
  const int tx = tid % 16;      // n-tile coord
  const int ty = tid / 16;      // m-tile coord
  const int n0 = blockIdx.x * 64;
  const int m0 = blockIdx.y * 64;

  // A-tile load mapping: 64 rows x 16 k, float4 per thread
  const int a_r = tid / 4;            // 0..63
  const int a_c = (tid % 4) * 4;      // 0,4,8,12
  // B-tile load mapping: 16 k x 64 n, float4 per thread
  const int b_r = tid / 16;           // 0..15
  const int b_c = (tid % 16) * 4;     // 0..60

  float acc[4][4];
#pragma unroll
  for (int i = 0; i < 4; ++i)
#pragma unroll
    for (int j = 0; j < 4; ++j) acc[i][j] = 0.f;

  for (int k0 = 0; k0 < K; k0 += 16) {
    float4 av = *(const float4*)(A + (size_t)(m0 + a_r) * K + k0 + a_c);
    float4 bv = *(const float4*)(W + (size_t)(k0 + b_r) * N + n0 + b_c);
    __syncthreads();  // previous iter's compute done before overwrite
    As[a_c + 0][a_r] = av.x;
    As[a_c + 1][a_r] = av.y;
    As[a_c + 2][a_r] = av.z;
    As[a_c + 3][a_r] = av.w;
    *(float4*)&Bs[b_r][b_c] = bv;
    __syncthreads();
#pragma unroll
    for (int kk = 0; kk < 16; ++kk) {
      float4 af = *(const float4*)&As[kk][ty * 4];
      float4 bf = *(const float4*)&Bs[kk][tx * 4];
      float aa[4] = {af.x, af.y, af.z, af.w};
      float bb[4] = {bf.x, bf.y, bf.z, bf.w};
#pragma unroll
      for (int i = 0; i < 4; ++i)
#pragma unroll
        for (int j = 0; j < 4; ++j) acc[i][j] += aa[i] * bb[j];
    }
  }

  const float4 bbias = *(const float4*)(bias + n0 + tx * 4);
#pragma unroll
  for (int i = 0; i < 4; ++i) {
    const int m = m0 + ty * 4 + i;
    float4 c = make_float4(acc[i][0] + bbias.x, acc[i][1] + bbias.y,
                           acc[i][2] + bbias.z, acc[i][3] + bbias.w);
    if (RES) {
      float4 r = *(const float4*)(R + (size_t)m * N + n0 + tx * 4);
      c.x += r.x; c.y += r.y; c.z += r.z; c.w += r.w;
    }
    if (RELU) {
      c.x = fmaxf(c.x, 0.f); c.y = fmaxf(c.y, 0.f);
      c.z = fmaxf(c.z, 0.f); c.w = fmaxf(c.w, 0.f);
    }
    *(float4*)(C + (size_t)m * N + n0 + tx * 4) = c;
  }
}

// ---------------------------------------------------------------------------
// LayerNorm over last dim (1024). One block per row, 256 threads (float4 each).
// ---------------------------------------------------------------------------
__global__ __launch_bounds__(256) void ln_kernel(const float* __restrict__ in,
                                                 float* __restrict__ out) {
  const int row = blockIdx.x;
  const int t = threadIdx.x;
  float4 v = ((const float4*)(in + (size_t)row * Dc))[t];
  float s = v.x + v.y + v.z + v.w;
  float s2 = v.x * v.x + v.y * v.y + v.z * v.z + v.w * v.w;
#pragma unroll
  for (int off = 32; off; off >>= 1) {
    s += __shfl_down(s, off);
    s2 += __shfl_down(s2, off);
  }
  __shared__ float red[2][4];
  const int wid = t / 64;
  if ((t & 63) == 0) { red[0][wid] = s; red[1][wid] = s2; }
  __syncthreads();
  s = red[0][0] + red[0][1] + red[0][2] + red[0][3];
  s2 = red[1][0] + red[1][1] + red[1][2] + red[1][3];
  const float mean = s * (1.f / Dc);
  const float var = s2 * (1.f / Dc) - mean * mean;
  const float inv = rsqrtf(var + LN_EPS);
  float4 o = make_float4((v.x - mean) * inv, (v.y - mean) * inv,
                         (v.z - mean) * inv, (v.w - mean) * inv);
  ((float4*)(out + (size_t)row * Dc))[t] = o;
}

// ---------------------------------------------------------------------------
// Fused attention for one (b, h, 16-row tile):
//   scores (LDS) -> mask -> softmax -> write attn to corrs -> AV in-block.
// grid = (S/16, H, B), 256 threads.
// ---------------------------------------------------------------------------
__global__ __launch_bounds__(256) void attn_kernel(
    const float* __restrict__ q, const float* __restrict__ k,
    const float* __restrict__ v, const int* __restrict__ enc,
    float* __restrict__ attn_out, float* __restrict__ av_out) {
  constexpr int AR = 16;
  const int rt = blockIdx.x;
  const int h = blockIdx.y;
  const int b = blockIdx.z;
  const int r0 = rt * AR;
  const int t = threadIdx.x;

  __shared__ float qs[AR][68];    // [r][d] padded
  __shared__ float kt[DHc][68];   // scores phase: [d][j]; av phase: [j][d]
  __shared__ float sc[AR][516];   // scores / attn row buffer, padded

  // Load q rows: 16 x 64 floats = 256 float4
  {
    const int r = t / 16;
    const int c4 = (t % 16) * 4;
    float4 qv = *(const float4*)(q + (size_t)(b * Sc + r0 + r) * Dc + h * DHc + c4);
    *(float4*)&qs[r][c4] = qv;
  }

  const int r = t / 16;           // 0..15 — this thread's score row
  const int j0 = (t % 16) * 4;    // 4 columns per thread within a 64-j tile

  // --- scores = q . k^T * inv_sqrt_dk ---
  for (int jt = 0; jt < Sc / 64; ++jt) {
    __syncthreads();  // protect kt reuse across iterations (and qs on iter 0)
    {
      const int j = t / 4;
      const int d0 = (t % 4) * 16;
      const float* krow = k + (size_t)(b * Sc + jt * 64 + j) * Dc + h * DHc + d0;
#pragma unroll
      for (int ii = 0; ii < 4; ++ii) {
        float4 kv = ((const float4*)krow)[ii];
        kt[d0 + ii * 4 + 0][j] = kv.x;
        kt[d0 + ii * 4 + 1][j] = kv.y;
        kt[d0 + ii * 4 + 2][j] = kv.z;
        kt[d0 + ii * 4 + 3][j] = kv.w;
      }
    }
    __syncthreads();
    float c0 = 0.f, c1 = 0.f, c2 = 0.f, c3 = 0.f;
#pragma unroll
    for (int d = 0; d < DHc; ++d) {
      const float qd = qs[r][d];
      float4 kv = *(const float4*)&kt[d][j0];
      c0 += qd * kv.x; c1 += qd * kv.y; c2 += qd * kv.z; c3 += qd * kv.w;
    }
    sc[r][jt * 64 + j0 + 0] = c0 * INV_SQRT_DK;
    sc[r][jt * 64 + j0 + 1] = c1 * INV_SQRT_DK;
    sc[r][jt * 64 + j0 + 2] = c2 * INV_SQRT_DK;
    sc[r][jt * 64 + j0 + 3] = c3 * INV_SQRT_DK;
  }
  __syncthreads();

  // --- masked softmax per row (16 lanes per row, lanes scan stride 16) ---
  const int lane16 = t % 16;
  float mx = NEG_BIG;
#pragma unroll
  for (int it = 0; it < 32; ++it) {
    const int j = lane16 + it * 16;
    float sv = sc[r][j];
    if (enc[b * Sc + j] == 0) sv = NEG_BIG;
    sc[r][j] = sv;
    mx = fmaxf(mx, sv);
  }
#pragma unroll
  for (int off = 8; off; off >>= 1) mx = fmaxf(mx, __shfl_xor(mx, off));
  float sum = 0.f;
#pragma unroll
  for (int it = 0; it < 32; ++it) {
    const int j = lane16 + it * 16;
    float e = __expf(sc[r][j] - mx);
    sc[r][j] = e;
    sum += e;
  }
#pragma unroll
  for (int off = 8; off; off >>= 1) sum += __shfl_xor(sum, off);
  const float inv = 1.f / sum;
  float* arow = attn_out + (((size_t)b * Hc + h) * Sc + (r0 + r)) * Sc;
#pragma unroll
  for (int it = 0; it < 32; ++it) {
    const int j = lane16 + it * 16;
    const float a = sc[r][j] * inv;
    sc[r][j] = a;
    arow[j] = a;
  }

  // --- AV = attn @ v ---  (reuse kt as [j][d] tile of v)
  const int d0 = (t % 16) * 4;
  float av0 = 0.f, av1 = 0.f, av2 = 0.f, av3 = 0.f;
  for (int jt = 0; jt < Sc / 64; ++jt) {
    __syncthreads();
    {
      const int j = t / 4;
      const int c0 = (t % 4) * 16;
      const float* vrow = v + (size_t)(b * Sc + jt * 64 + j) * Dc + h * DHc + c0;
#pragma unroll
      for (int ii = 0; ii < 4; ++ii) {
        float4 vv = ((const float4*)vrow)[ii];
        *(float4*)&kt[j][c0 + ii * 4] = vv;
      }
    }
    __syncthreads();
#pragma unroll
    for (int j = 0; j < 64; ++j) {
      const float a = sc[r][jt * 64 + j];
      float4 vv = *(const float4*)&kt[j][d0];
      av0 += a * vv.x; av1 += a * vv.y; av2 += a * vv.z; av3 += a * vv.w;
    }
  }
  *(float4*)(av_out + (size_t)(b * Sc + r0 + r) * Dc + h * DHc + d0) =
      make_float4(av0, av1, av2, av3);
}

// ---------------------------------------------------------------------------
// Launch
// ---------------------------------------------------------------------------
extern "C" void kernel_launch(void* const* d_in, const int* in_sizes, int n_in,
                              void* d_out, int out_size, void* d_ws,
                              size_t ws_size, hipStream_t stream) {
  const int* enc = (const int*)d_in[0];
  const float* we = (const float*)d_in[1];
  const float* pt = (const float*)d_in[2];
  const float* Wq = (const float*)d_in[3];
  const float* bq = (const float*)d_in[4];
  const float* Wk = (const float*)d_in[5];
  const float* bk = (const float*)d_in[6];
  const float* Wv = (const float*)d_in[7];
  const float* bv = (const float*)d_in[8];
  const float* Wo = (const float*)d_in[9];
  const float* bo = (const float*)d_in[10];
  const float* W1 = (const float*)d_in[11];
  const float* b1 = (const float*)d_in[12];
  const float* W2 = (const float*)d_in[13];
  const float* b2 = (const float*)d_in[14];

  float* out = (float*)d_out;
  float* corrs = out + (size_t)Mrows * Dc;  // 2,097,152 floats in

  constexpr size_t NMD = (size_t)Mrows * Dc;    // 2048*1024
  constexpr size_t NMF = (size_t)Mrows * DFFc;  // 2048*4096
  float* ws = (float*)d_ws;
  float* X  = ws;            // layer input
  float* Q  = X + NMD;
  float* Kb = Q + NMD;       // also reused as T (post-attn pre-LN)
  float* Vb = Kb + NMD;      // also reused as X1
  float* AV = Vb + NMD;
  float* FF = AV + NMD;      // 2048*4096
  // total: 5*NMD + NMF = 18.9M floats = 75.5 MB

  const dim3 blk(256);
  embed_kernel<<<Mrows, blk, 0, stream>>>(enc, we, pt, X);

  for (int l = 0; l < Lc; ++l) {
    const float* wq = Wq + (size_t)l * Dc * Dc;
    const float* wk = Wk + (size_t)l * Dc * Dc;
    const float* wv = Wv + (size_t)l * Dc * Dc;
    const float* wo = Wo + (size_t)l * Dc * Dc;
    const float* w1 = W1 + (size_t)l * Dc * DFFc;
    const float* w2 = W2 + (size_t)l * DFFc * Dc;
    const float* lbq = bq + (size_t)l * Dc;
    const float* lbk = bk + (size_t)l * Dc;
    const float* lbv = bv + (size_t)l * Dc;
    const float* lbo = bo + (size_t)l * Dc;
    const float* lb1 = b1 + (size_t)l * DFFc;
    const float* lb2 = b2 + (size_t)l * Dc;

    const dim3 g1024(Dc / 64, Mrows / 64);   // (16, 32)
    const dim3 g4096(DFFc / 64, Mrows / 64); // (64, 32)

    gemm_kernel<false, false><<<g1024, blk, 0, stream>>>(X, wq, lbq, nullptr, Q, Dc, Dc);
    gemm_kernel<false, false><<<g1024, blk, 0, stream>>>(X, wk, lbk, nullptr, Kb, Dc, Dc);
    gemm_kernel<false, false><<<g1024, blk, 0, stream>>>(X, wv, lbv, nullptr, Vb, Dc, Dc);

    float* lcorr = corrs + (size_t)l * Bc * Hc * Sc * Sc;
    attn_kernel<<<dim3(Sc / 16, Hc, Bc), blk, 0, stream>>>(Q, Kb, Vb, enc, lcorr, AV);

    // T = X + AV@Wo + bo  (write into Kb, which is free now)
    gemm_kernel<false, true><<<g1024, blk, 0, stream>>>(AV, wo, lbo, X, Kb, Dc, Dc);
    // X1 = LN(T) -> Vb
    ln_kernel<<<Mrows, blk, 0, stream>>>(Kb, Vb);
    // FF = relu(X1@W1 + b1)
    gemm_kernel<true, false><<<g4096, blk, 0, stream>>>(Vb, w1, lb1, nullptr, FF, DFFc, Dc);
    // T2 = X1 + FF@W2 + b2 (write into Q, free)
    gemm_kernel<false, true><<<g1024, blk, 0, stream>>>(FF, w2, lb2, Vb, Q, Dc, DFFc);
    // X = LN(T2); last layer writes straight to d_out
    ln_kernel<<<Mrows, blk, 0, stream>>>(Q, (l == Lc - 1) ? out : X);
  }
}